// Round 4
// baseline (202.749 us; speedup 1.0000x reference)
//
#include <hip/hip_runtime.h>

#define NB    32
#define NP    65536
#define SZ    64
#define SZ3   (SZ * SZ * SZ)     // 262144
#define KS    21
#define HALF  10
#define NBINZ 65                 // z-bins: i2+1, i2 in [-1,63]
#define CAPZ  2048               // per-bin capacity (worst-case ~1500)
#define PL_W  72                 // plane row stride (words)
#define PL_WORDS (70 * PL_W)     // 70 rows x 72 cols f32 (guard band 2 each side)

typedef _Float16 half8_t __attribute__((ext_vector_type(8)));
typedef _Float16 half4_t __attribute__((ext_vector_type(4)));
typedef float    f32x4_t __attribute__((ext_vector_type(4)));

// XOR-swizzled tile address: rows x 64 cols of f16, 16B-chunk swizzle.
__device__ __forceinline__ int swz(int row, int col) {
    return (row << 6) + ((((col >> 3) ^ (row & 7))) << 3) + (col & 7);
}

// Normalized Gaussian taps (sigma=3) into registers
__device__ __forceinline__ void weights_reg(float* w) {
    float sum = 0.0f;
#pragma unroll
    for (int k = 0; k < KS; ++k) {
        float d = (float)k - (float)HALF;
        w[k] = expf(-d * d / 18.0f);
        sum += w[k];
    }
#pragma unroll
    for (int k = 0; k < KS; ++k) w[k] /= sum;
}

__device__ __forceinline__ void fma4(float4& a, float t, const float4& v) {
    a.x = fmaf(t, v.x, a.x); a.y = fmaf(t, v.y, a.y);
    a.z = fmaf(t, v.z, a.z); a.w = fmaf(t, v.w, a.w);
}

__device__ __forceinline__ unsigned short h16(float x) {
    _Float16 h = (_Float16)x;
    return __builtin_bit_cast(unsigned short, h);
}
__device__ __forceinline__ float f16f(unsigned v) {
    return (float)__builtin_bit_cast(_Float16, (unsigned short)(v & 0xffffu));
}

// ---- 1. fill z-bins with precomputed (i0,i1, r0,r1,fz) packed points ----
__global__ void fill_kernel(const float* __restrict__ pc,
                            const float* __restrict__ rot,
                            int* __restrict__ cur,
                            uint2* __restrict__ binned,
                            _Float16* __restrict__ Gg) {
    __shared__ int h[4][NBINZ];
    __shared__ int woff[4][NBINZ];
    __shared__ int lbase[NBINZ];
    int base = blockIdx.x * 1024;          // 4 points/thread, block within one batch
    int b = base >> 16;
    int wv = threadIdx.x >> 6;
    for (int i = threadIdx.x; i < 4 * NBINZ; i += 256) h[i / NBINZ][i % NBINZ] = 0;
    __syncthreads();
    const float* R = rot + b * 9;
    const float4* p4 = (const float4*)(pc + (size_t)base * 3);
    float4 f0v = p4[threadIdx.x * 3 + 0];
    float4 f1v = p4[threadIdx.x * 3 + 1];
    float4 f2v = p4[threadIdx.x * 3 + 2];
    float px[4] = {f0v.x, f0v.w, f1v.z, f2v.y};
    float py[4] = {f0v.y, f1v.x, f1v.w, f2v.z};
    float pz[4] = {f0v.z, f1v.y, f2v.x, f2v.w};
    uint2 pk[4];
    int bn[4], lp[4];
#pragma unroll
    for (int j = 0; j < 4; ++j) {
        float g0 = (R[0] * px[j] + R[1] * py[j] + R[2] * pz[j] + 0.5f) * 63.0f;
        float g1 = (R[3] * px[j] + R[4] * py[j] + R[5] * pz[j] + 0.5f) * 63.0f;
        float g2 = (R[6] * px[j] + R[7] * py[j] + R[8] * pz[j] + 0.5f) * 63.0f;
        float fl0 = floorf(g0), fl1 = floorf(g1), fl2 = floorf(g2);
        int i2 = (int)fl2;
        // clamp cell indices into the guard band [-2,65] -> [0,67]; OOB rows/
        // cols land in guard cells that the consumer never reads back.
        int i0c = min(max((int)fl0, -2), 65);
        int i1c = min(max((int)fl1, -2), 65);
        pk[j].x = (unsigned)(i0c + 2) | ((unsigned)(i1c + 2) << 8)
                | ((unsigned)h16(g0 - fl0) << 16);
        pk[j].y = (unsigned)h16(g1 - fl1) | ((unsigned)h16(g2 - fl2) << 16);
        bn[j] = (i2 >= -1 && i2 <= 63) ? (i2 + 1) : -1;
        if (bn[j] >= 0) lp[j] = atomicAdd(&h[wv][bn[j]], 1);
    }
    __syncthreads();
    if (threadIdx.x < NBINZ) {
        int t = threadIdx.x;
        int s0 = h[0][t], s1 = h[1][t], s2 = h[2][t], s3 = h[3][t];
        int tot = s0 + s1 + s2 + s3;
        lbase[t] = tot ? atomicAdd(&cur[b * NBINZ + t], tot) : 0;
        woff[0][t] = 0; woff[1][t] = s0; woff[2][t] = s0 + s1; woff[3][t] = s0 + s1 + s2;
    }
    __syncthreads();
#pragma unroll
    for (int j = 0; j < 4; ++j) {
        if (bn[j] >= 0) {
            int pos = lbase[bn[j]] + woff[wv][bn[j]] + lp[j];
            if (pos < CAPZ)
                binned[(size_t)(b * NBINZ + bn[j]) * CAPZ + pos] = pk[j];
        }
    }
    // G[o][k] = g[o-k+10] (zero outside band), row-major stride 64
    if (blockIdx.x == 0) {
        float w[KS];
        weights_reg(w);
        for (int i = threadIdx.x; i < 4096; i += 256) {
            int d = (i >> 6) - (i & 63) + HALF;
            Gg[i] = ((unsigned)d < (unsigned)KS) ? (_Float16)w[d] : (_Float16)0.0f;
        }
    }
}

// ---- 2. ds_add_f32 splat into guard-banded f32 plane + MFMA blur ----
// One block per (b,z). 4 waves stride the concatenated 2-bin point stream,
// each point does 4 native LDS f32 atomic adds into a [70][72] plane (guard
// band absorbs out-of-range contributions -> zero clamping logic). Then
// clip->f16 P tile and the proven 2-pass MFMA blur (4 waves x 16 rows).
__global__ void __launch_bounds__(256, 5) splat_blur(const uint2* __restrict__ binned,
                                                     const int* __restrict__ cur,
                                                     const _Float16* __restrict__ Gg,
                                                     _Float16* __restrict__ vox) {
    // plane declared DIRECTLY as __shared__ float so address-space inference
    // is trivial and the atomic below lowers to ds_add_f32 (round-2's char*
    // overlay produced a flat CAS loop -> 119us latency-bound disaster).
    __shared__ __align__(16) float plane[PL_WORDS];
    __shared__ __align__(16) _Float16 Ptile[4096];
    _Float16* P = Ptile;
    _Float16* T = (_Float16*)plane;       // overlay: plane dead after P built

    int tid = threadIdx.x;
    int w = tid >> 6, lane = tid & 63;
    int idx = blockIdx.x;
    int b = idx >> 6;
    int k = (idx + (b << 3)) & 63;                        // shear for per-CU mix
    int z = (k & 1) ? (31 - (k >> 1)) : (32 + (k >> 1));  // center-out (LPT)
    int q = lane >> 4, c = lane & 15;

    {   // zero plane
        int4 z4 = {0, 0, 0, 0};
        int4* p4 = (int4*)plane;
        for (int i = tid; i < PL_WORDS / 4; i += 256) p4[i] = z4;
    }
    __syncthreads();

    // concatenated stream: bin z (az = fz), then bin z+1 (az = 1-fz)
    int c0 = min(cur[b * NBINZ + z],     CAPZ);
    int c1 = min(cur[b * NBINZ + z + 1], CAPZ);
    int n = c0 + c1;
    const uint2* s0 = binned + (size_t)(b * NBINZ + z) * CAPZ;  // s1 = s0 + CAPZ

    int iters = (n + 255) >> 8;
    uint2 pA = make_uint2(0u, 0u), pB = make_uint2(0u, 0u);  // pk=0 -> guard cell
    int fA = 0, fB = 0;
    {
        int i0g = tid;
        if (i0g < n) { fA = i0g >= c0; pA = s0[i0g + (fA ? CAPZ - c0 : 0)]; }
        int i1g = 256 + tid;
        if (i1g < n) { fB = i1g >= c0; pB = s0[i1g + (fB ? CAPZ - c0 : 0)]; }
    }
    for (int it = 0; it < iters; ++it) {
        uint2 pk = pA; int fk = fA;
        pA = pB; fA = fB;
        pB = make_uint2(0u, 0u); fB = 0;
        int ni = (it + 2) * 256 + tid;                    // prefetch depth 2
        if (ni < n) { fB = ni >= c0; pB = s0[ni + (fB ? CAPZ - c0 : 0)]; }

        int col = pk.x & 0xff;
        int row = (pk.x >> 8) & 0xff;
        float r0 = f16f(pk.x >> 16);
        float r1 = f16f(pk.y);
        float fz = f16f(pk.y >> 16);
        float az  = fk ? 1.0f - fz : fz;
        float ay1 = az * r1;
        float ay0 = az - ay1;
        float w01 = ay0 * r0;
        float w00 = ay0 - w01;
        float w11 = ay1 * r0;
        float w10 = ay1 - w11;
        int cell = row * PL_W + col;
        __hip_atomic_fetch_add(&plane[cell],            w00,
                               __ATOMIC_RELAXED, __HIP_MEMORY_SCOPE_WORKGROUP);
        __hip_atomic_fetch_add(&plane[cell + 1],        w01,
                               __ATOMIC_RELAXED, __HIP_MEMORY_SCOPE_WORKGROUP);
        __hip_atomic_fetch_add(&plane[cell + PL_W],     w10,
                               __ATOMIC_RELAXED, __HIP_MEMORY_SCOPE_WORKGROUP);
        __hip_atomic_fetch_add(&plane[cell + PL_W + 1], w11,
                               __ATOMIC_RELAXED, __HIP_MEMORY_SCOPE_WORKGROUP);
    }
    __syncthreads();                                  // B1: plane accumulated

    // G fragments (pass1 B-operand [all 4] and pass2 A-operand [own w])
    half8_t gf[4][2];
#pragma unroll
    for (int ni = 0; ni < 4; ++ni)
#pragma unroll
        for (int hh = 0; hh < 2; ++hh)
            gf[ni][hh] = *(const half8_t*)&Gg[(ni * 16 + c) * 64 + hh * 32 + q * 8];

    // clip + convert real 64x64 window into swizzled f16 P tile
    for (int i = tid; i < 4096; i += 256) {
        int Y = i >> 6, X = i & 63;
        float v = plane[(Y + 2) * PL_W + (X + 2)];
        P[swz(Y, X)] = (_Float16)fminf(fmaxf(v, 0.0f), 1.0f);
    }
    __syncthreads();                                  // B2: P complete

    // pass1 (x-blur): wave w computes output rows [16w, 16w+16)
    f32x4_t a2[4];
#pragma unroll
    for (int ni = 0; ni < 4; ++ni) a2[ni] = (f32x4_t){0.f, 0.f, 0.f, 0.f};
#pragma unroll
    for (int hh = 0; hh < 2; ++hh) {
        half8_t af1 = *(const half8_t*)&P[swz(w * 16 + c, hh * 32 + q * 8)];
#pragma unroll
        for (int ni = 0; ni < 4; ++ni)
            a2[ni] = __builtin_amdgcn_mfma_f32_16x16x32_f16(
                af1, gf[ni][hh], a2[ni], 0, 0, 0);
    }
    // transpose into T (overlays dead plane; disjoint from P)
#pragma unroll
    for (int ni = 0; ni < 4; ++ni) {
        half4_t pkd;
#pragma unroll
        for (int r = 0; r < 4; ++r) pkd[r] = (_Float16)a2[ni][r];
        *(half4_t*)&T[swz(ni * 16 + c, w * 16 + q * 4)] = pkd;
    }
    __syncthreads();                                  // B3: T complete

    // pass2 (y-blur): wave w computes output rows [16w, 16w+16)
    f32x4_t a3[4];
#pragma unroll
    for (int ni = 0; ni < 4; ++ni) a3[ni] = (f32x4_t){0.f, 0.f, 0.f, 0.f};
#pragma unroll
    for (int hh = 0; hh < 2; ++hh) {
        half8_t bf1[4];
#pragma unroll
        for (int ni = 0; ni < 4; ++ni)
            bf1[ni] = *(const half8_t*)&T[swz(ni * 16 + c, hh * 32 + q * 8)];
#pragma unroll
        for (int ni = 0; ni < 4; ++ni)
            a3[ni] = __builtin_amdgcn_mfma_f32_16x16x32_f16(
                gf[w][hh], bf1[ni], a3[ni], 0, 0, 0);
    }

    // store f16 rows
    _Float16* dst = vox + ((size_t)b << 18) + ((size_t)z << 12);
#pragma unroll
    for (int ni = 0; ni < 4; ++ni)
#pragma unroll
        for (int r = 0; r < 4; ++r)
            dst[((w * 16 + q * 4 + r) << 6) + ni * 16 + c] = (_Float16)a3[ni][r];
}

// ---- 3. fused conv along z (f16 in) + scale/clip + segmented DRC + y-flip ----
__global__ void convz_drc_kernel(const _Float16* __restrict__ in,
                                 const float* __restrict__ scale,
                                 float* __restrict__ out) {
    __shared__ float sraw[640 + SZ * SZ + 640];  // 10-row zero guards each side
    __shared__ float c[SZ * SZ];
    __shared__ float segS[4][64], segT[4][64];
    float* s = sraw + 640;
    int b = blockIdx.x >> 6, y = blockIdx.x & 63;

    for (int i = threadIdx.x; i < 640; i += 256) {
        sraw[i] = 0.0f;
        sraw[640 + SZ * SZ + i] = 0.0f;
    }
    const _Float16* base = in + ((size_t)b << 18) + (y << 6);
#pragma unroll
    for (int g = 0; g < 4; ++g) {
        int cell = g * 256 + threadIdx.x;        // 1024 half4 cells
        int z = cell >> 4, xc = (cell & 15) << 2;
        half4_t v = *(const half4_t*)&base[((size_t)z << 12) + xc];
        float4 f = make_float4((float)v[0], (float)v[1], (float)v[2], (float)v[3]);
        *(float4*)&s[(z << 6) + xc] = f;
    }
    __syncthreads();

    float w[KS];
    weights_reg(w);

    {   // z-conv: one (z-group-of-4, x-chunk) per thread, 24 b128 reads
        int z0 = (threadIdx.x >> 4) << 2;
        int xc = (threadIdx.x & 15) << 2;
        float4 a0 = {0,0,0,0}, a1 = {0,0,0,0}, a2 = {0,0,0,0}, a3 = {0,0,0,0};
#pragma unroll
        for (int d = 0; d < 24; ++d) {
            int zz = z0 - HALF + d;              // guards cover [-10, 73]
            float4 v = *(const float4*)&s[(zz << 6) + xc];
            if (d <= 20)           fma4(a0, w[d],     v);
            if (d >= 1 && d <= 21) fma4(a1, w[d - 1], v);
            if (d >= 2 && d <= 22) fma4(a2, w[d - 2], v);
            if (d >= 3)            fma4(a3, w[d - 3], v);
        }
        *(float4*)&c[((z0 + 0) << 6) + xc] = a0;
        *(float4*)&c[((z0 + 1) << 6) + xc] = a1;
        *(float4*)&c[((z0 + 2) << 6) + xc] = a2;
        *(float4*)&c[((z0 + 3) << 6) + xc] = a3;
    }
    __syncthreads();

    {   // segmented DRC march: 4 z-segments x 64 columns
        int x = threadIdx.x & 63, seg = threadIdx.x >> 6;
        float sc = scale[b];
        float trans = 1.0f, sum = 0.0f;
#pragma unroll
        for (int zz = 0; zz < 16; ++zz) {
            int z = seg * 16 + zz;
            float v = fminf(fmaxf(c[(z << 6) + x] * sc, 0.0f), 1.0f);
            sum += v * trans;
            trans *= 1.0f - v;
        }
        segS[seg][x] = sum;
        segT[seg][x] = trans;
    }
    __syncthreads();
    if (threadIdx.x < 64) {
        int x = threadIdx.x;
        float t = 1.0f, S = 0.0f;
#pragma unroll
        for (int sgi = 0; sgi < 4; ++sgi) { S += segS[sgi][x] * t; t *= segT[sgi][x]; }
        out[(b << 12) + ((63 - y) << 6) + x] = S;
    }
}

extern "C" void kernel_launch(void* const* d_in, const int* in_sizes, int n_in,
                              void* d_out, int out_size, void* d_ws, size_t ws_size,
                              hipStream_t stream) {
    const float* pc    = (const float*)d_in[0];
    const float* rot   = (const float*)d_in[1];
    const float* scale = (const float*)d_in[2];
    float* out = (float*)d_out;

    // ws: vox f16 16.8 MB | binned z-bins 34.1 MB | G 8 KB | cursors 8.3 KB
    _Float16* vox    = (_Float16*)d_ws;
    uint2*    binned = (uint2*)((char*)d_ws + (size_t)NB * SZ3 * sizeof(_Float16));
    _Float16* Gg     = (_Float16*)((char*)binned + (size_t)NB * NBINZ * CAPZ * sizeof(uint2));
    int*      cur    = (int*)((char*)Gg + 64 * 64 * sizeof(_Float16));

    hipMemsetAsync(cur, 0, NB * NBINZ * sizeof(int), stream);

    fill_kernel     <<<NB * NP / 1024, 256, 0, stream>>>(pc, rot, cur, binned, Gg);
    splat_blur      <<<NB * SZ, 256, 0, stream>>>(binned, cur, Gg, vox);
    convz_drc_kernel<<<NB * SZ, 256, 0, stream>>>(vox, scale, out);
}

// Round 5
// 129.799 us; speedup vs baseline: 1.5620x; 1.5620x over previous
//
#include <hip/hip_runtime.h>

#define NB    32
#define NP    65536
#define SZ    64
#define SZ3   (SZ * SZ * SZ)     // 262144
#define KS    21
#define HALF  10
#define NBIN2 130                // sub-bins: (i2+1)*2 + yhalf, i2 in [-1,63]
#define CAP2  1280               // fixed sub-bin capacity (max expected ~900)

typedef _Float16 half8_t __attribute__((ext_vector_type(8)));
typedef _Float16 half4_t __attribute__((ext_vector_type(4)));
typedef float    f32x4_t __attribute__((ext_vector_type(4)));

// XOR-swizzled tile address: rows x 64 cols of f16, 16B-chunk swizzle.
__device__ __forceinline__ int swz(int row, int col) {
    return (row << 6) + ((((col >> 3) ^ (row & 7))) << 3) + (col & 7);
}
// identity for col==lane (<64): swz(r,lane) = ((r<<6)|((r&7)<<3)) ^ lane
__device__ __forceinline__ int swzl(int row, int lane) {
    return (((row << 6) | ((row & 7) << 3)) ^ lane);
}

// Normalized Gaussian taps (sigma=3) into registers
__device__ __forceinline__ void weights_reg(float* w) {
    float sum = 0.0f;
#pragma unroll
    for (int k = 0; k < KS; ++k) {
        float d = (float)k - (float)HALF;
        w[k] = expf(-d * d / 18.0f);
        sum += w[k];
    }
#pragma unroll
    for (int k = 0; k < KS; ++k) w[k] /= sum;
}

__device__ __forceinline__ void fma4(float4& a, float t, const float4& v) {
    a.x = fmaf(t, v.x, a.x); a.y = fmaf(t, v.y, a.y);
    a.z = fmaf(t, v.z, a.z); a.w = fmaf(t, v.w, a.w);
}

__device__ __forceinline__ unsigned h16(float x) {
    _Float16 h = (_Float16)x;
    return (unsigned)__builtin_bit_cast(unsigned short, h);
}
__device__ __forceinline__ float f16f(unsigned v) {
    return (float)__builtin_bit_cast(_Float16, (unsigned short)(v & 0xffffu));
}

// ---- 1. fill (z, y-half) sub-bins; 8B entries, consumer-light packing ----
// entry.x = f16(r0) | f16(r1)<<16
// entry.y = f16(fz) | (rlo&63)<<16 | (i0&255)<<22
//   rlo = i1 - 32*(bin's y-half)  in [-1,31]  (6-bit signed)
//   i0  = clamp(floor(g0), -2, 65)            (8-bit signed)
__global__ void fill_kernel(const float* __restrict__ pc,
                            const float* __restrict__ rot,
                            int* __restrict__ cur,
                            uint2* __restrict__ binned,
                            _Float16* __restrict__ Gg) {
    __shared__ int h[4][NBIN2];
    __shared__ int woff[4][NBIN2];
    __shared__ int lbase[NBIN2];
    int base = blockIdx.x * 1024;          // 4 points/thread, block within one batch
    int b = base >> 16;
    int wv = threadIdx.x >> 6;
    for (int i = threadIdx.x; i < 4 * NBIN2; i += 256) h[i / NBIN2][i % NBIN2] = 0;
    __syncthreads();
    const float* R = rot + b * 9;
    const float4* p4 = (const float4*)(pc + (size_t)base * 3);
    float4 f0 = p4[threadIdx.x * 3 + 0];
    float4 f1 = p4[threadIdx.x * 3 + 1];
    float4 f2 = p4[threadIdx.x * 3 + 2];
    float px[4] = {f0.x, f0.w, f1.z, f2.y};
    float py[4] = {f0.y, f1.x, f1.w, f2.z};
    float pz[4] = {f0.z, f1.y, f2.x, f2.w};
    uint2 pk[4][2];                        // per-half variants (differ in .y)
    int bin0[4], bin1[4], lp0[4], lp1[4];
#pragma unroll
    for (int j = 0; j < 4; ++j) {
        float g0 = (R[0] * px[j] + R[1] * py[j] + R[2] * pz[j] + 0.5f) * 63.0f;
        float g1 = (R[3] * px[j] + R[4] * py[j] + R[5] * pz[j] + 0.5f) * 63.0f;
        float g2 = (R[6] * px[j] + R[7] * py[j] + R[8] * pz[j] + 0.5f) * 63.0f;
        float fl0 = floorf(g0), fl1 = floorf(g1), fl2 = floorf(g2);
        int i0 = (int)fl0, i1 = (int)fl1, i2 = (int)fl2;
        bool zv = (i2 >= -1 && i2 <= 63);
        int h0 = ((unsigned)i1       < 64u) ? (i1 >> 5)       : -1;
        int h1 = ((unsigned)(i1 + 1) < 64u) ? ((i1 + 1) >> 5) : -1;
        if (h1 == h0) h1 = -1;
        bin0[j] = (zv && h0 >= 0) ? ((i2 + 1) * 2 + h0) : -1;
        bin1[j] = (zv && h1 >= 0) ? ((i2 + 1) * 2 + h1) : -1;

        int i0c = min(max(i0, -2), 65);
        unsigned ex = h16(g0 - fl0) | (h16(g1 - fl1) << 16);
        unsigned eyb = h16(g2 - fl2) | (((unsigned)i0c & 255u) << 22);
#pragma unroll
        for (int s = 0; s < 2; ++s) {
            int hs = s ? h1 : h0;
            int rlo = i1 - ((hs > 0) << 5);
            pk[j][s].x = ex;
            pk[j][s].y = eyb | (((unsigned)rlo & 63u) << 16);
        }
        if (bin0[j] >= 0) lp0[j] = atomicAdd(&h[wv][bin0[j]], 1);
        if (bin1[j] >= 0) lp1[j] = atomicAdd(&h[wv][bin1[j]], 1);
    }
    __syncthreads();
    if (threadIdx.x < NBIN2) {
        int t = threadIdx.x;
        int s0 = h[0][t], s1 = h[1][t], s2 = h[2][t], s3 = h[3][t];
        int tot = s0 + s1 + s2 + s3;
        lbase[t] = tot ? atomicAdd(&cur[b * NBIN2 + t], tot) : 0;
        woff[0][t] = 0; woff[1][t] = s0; woff[2][t] = s0 + s1; woff[3][t] = s0 + s1 + s2;
    }
    __syncthreads();
#pragma unroll
    for (int j = 0; j < 4; ++j) {
        if (bin0[j] >= 0) {
            int pos = lbase[bin0[j]] + woff[wv][bin0[j]] + lp0[j];
            if (pos < CAP2)
                binned[(size_t)(b * NBIN2 + bin0[j]) * CAP2 + pos] = pk[j][0];
        }
        if (bin1[j] >= 0) {
            int pos = lbase[bin1[j]] + woff[wv][bin1[j]] + lp1[j];
            if (pos < CAP2)
                binned[(size_t)(b * NBIN2 + bin1[j]) * CAP2 + pos] = pk[j][1];
        }
    }
    // G[o][k] = g[o-k+10] (zero outside band), row-major stride 64
    if (blockIdx.x == 0) {
        float w[KS];
        weights_reg(w);
        for (int i = threadIdx.x; i < 4096; i += 256) {
            int d = (i >> 6) - (i & 63) + HALF;
            Gg[i] = ((unsigned)d < (unsigned)KS) ? (_Float16)w[d] : (_Float16)0.0f;
        }
    }
}

// ---- 2. MFMA splat + blur. TWO WAVES per (b,z): each owns one y-half. ----
// Wave w scatters its y-half's points into a 33x64 A-tile and 65x64 B-tile,
// accumulating a 32x64 half-C; both waves then cooperatively blur the shared
// plane. Fragment-read offsets hoisted out of the hot loop (round-1 profile:
// VALUBusy 72% dominated by rematerialized swz() address arithmetic).
__global__ void __launch_bounds__(128) splat_blur(const uint2* __restrict__ binned,
                                                  const int* __restrict__ cur,
                                                  const _Float16* __restrict__ Gg,
                                                  _Float16* __restrict__ vox) {
    // layout: A0[0,4224) A1[4224,8448) B0[8448,16768) B1[16768,25088)
    // overlays (dead after scatter): P=[0,8192)  T=[8448,16640)
    __shared__ __align__(16) char smem[25088];
    int tid = threadIdx.x;
    int w = tid >> 6, lane = tid & 63;
    int idx = blockIdx.x;
    int b = idx >> 6;
    int k = (idx + (b << 3)) & 63;                    // shear for per-CU mix
    int z = (k & 1) ? (31 - (k >> 1)) : (32 + (k >> 1));  // center-out (LPT)
    int q = lane >> 4, c = lane & 15;

    _Float16* Ay = (_Float16*)(smem + w * 4224);      // 33 rows (32 real + dummy 32)
    _Float16* Bx = (_Float16*)(smem + 8448 + w * 8320); // 65 rows (dummy 64)
    _Float16* P  = (_Float16*)smem;
    _Float16* T  = (_Float16*)(smem + 8448);

    {   // zero own tiles (wave-local, wave-ordered)
        int4 z4 = {0, 0, 0, 0};
        int4* a4 = (int4*)Ay;
        for (int i = lane; i < 4224 / 16; i += 64) a4[i] = z4;
        int4* b4 = (int4*)Bx;
        for (int i = lane; i < 8320 / 16; i += 64) b4[i] = z4;
    }

    // hoisted fragment byte-offsets (A uses rows 0..1, B rows 0..3)
    int foff[4][2];
#pragma unroll
    for (int ni = 0; ni < 4; ++ni)
#pragma unroll
        for (int hh = 0; hh < 2; ++hh)
            foff[ni][hh] = swz(ni * 16 + c, hh * 32 + q * 8);

    // this wave's sub-bins: (i2=z-1, w) and (i2=z, w)  -> 2 bins apart
    int c0 = min(cur[b * NBIN2 + 2 * z + w],       CAP2);
    int c1 = min(cur[b * NBIN2 + 2 * (z + 1) + w], CAP2);
    const uint2* s0 = binned + (size_t)(b * NBIN2 + 2 * z + w) * CAP2;
    int n = c0 + c1;

    f32x4_t acc[2][4];
#pragma unroll
    for (int ml = 0; ml < 2; ++ml)
#pragma unroll
        for (int ni = 0; ni < 4; ++ni) acc[ml][ni] = (f32x4_t){0.f, 0.f, 0.f, 0.f};

    // padding entry: rlo=32 (sign-ext -> -32 -> dummy rows), i0=64 (dummy cols)
    const uint2 pkz = make_uint2(0u, (32u << 16) | (64u << 22));
    int iters = (n + 63) >> 6;
    uint2 nxtA = pkz, nxtB = pkz;
    int fA = 0, fB = 0;
    {
        int i0g = lane;
        if (i0g < n) { fA = i0g >= c0; nxtA = s0[i0g + (fA ? 2 * CAP2 - c0 : 0)]; }
        int i1g = 64 + lane;
        if (i1g < n) { fB = i1g >= c0; nxtB = s0[i1g + (fB ? 2 * CAP2 - c0 : 0)]; }
    }
    int ni2 = 128 + lane;                             // prefetch depth 2
    for (int it = 0; it < iters; ++it) {
        uint2 pk = nxtA; int fk = fA;
        nxtA = nxtB; fA = fB;
        nxtB = pkz; fB = 0;
        if (ni2 < n) { fB = ni2 >= c0; nxtB = s0[ni2 + (fB ? 2 * CAP2 - c0 : 0)]; }
        ni2 += 64;

        float r0 = f16f(pk.x);
        float r1 = f16f(pk.x >> 16);
        float fz = f16f(pk.y);
        int rlo = ((int)(pk.y << 10)) >> 26;          // 6-bit signed @16
        int i0  = ((int)(pk.y << 2))  >> 24;          // 8-bit signed @22
        float az  = fk ? 1.0f - fz : fz;
        float ay1 = az * r1;
        float ay0 = az - ay1;
        int alo = ((unsigned)rlo       < 32u) ? rlo       : 32;  // dummy 32
        int ahi = ((unsigned)(rlo + 1) < 32u) ? (rlo + 1) : 32;
        int xlo = ((unsigned)i0        < 64u) ? i0        : 64;  // dummy 64
        int xhi = ((unsigned)(i0 + 1)  < 64u) ? (i0 + 1)  : 64;
        int aAlo = swzl(alo, lane), aAhi = swzl(ahi, lane);
        int aXlo = swzl(xlo, lane), aXhi = swzl(xhi, lane);
        Ay[aAlo] = (_Float16)ay0;
        Ay[aAhi] = (_Float16)ay1;
        Bx[aXlo] = (_Float16)(1.0f - r0);
        Bx[aXhi] = (_Float16)r0;
#pragma unroll
        for (int hh = 0; hh < 2; ++hh) {
            half8_t af[2], bf[4];
#pragma unroll
            for (int ml = 0; ml < 2; ++ml)
                af[ml] = *(const half8_t*)&Ay[foff[ml][hh]];
#pragma unroll
            for (int ni = 0; ni < 4; ++ni)
                bf[ni] = *(const half8_t*)&Bx[foff[ni][hh]];
#pragma unroll
            for (int ml = 0; ml < 2; ++ml)
#pragma unroll
                for (int ni = 0; ni < 4; ++ni)
                    acc[ml][ni] = __builtin_amdgcn_mfma_f32_16x16x32_f16(
                        af[ml], bf[ni], acc[ml][ni], 0, 0, 0);
        }
        // re-zero exactly what we wrote (after the frag reads; wave-ordered)
        Ay[aAlo] = (_Float16)0.0f;
        Ay[aAhi] = (_Float16)0.0f;
        Bx[aXlo] = (_Float16)0.0f;
        Bx[aXhi] = (_Float16)0.0f;
    }

    __syncthreads();                                  // B1: all scatter done

    // G fragments (loaded after scatter to cut hot-loop VGPR pressure)
    half8_t gf[4][2];
#pragma unroll
    for (int ni = 0; ni < 4; ++ni)
#pragma unroll
        for (int hh = 0; hh < 2; ++hh)
            gf[ni][hh] = *(const half8_t*)&Gg[(ni * 16 + c) * 64 + hh * 32 + q * 8];

    // each wave writes its clipped half-plane into shared P (overlay A0/A1)
#pragma unroll
    for (int ml = 0; ml < 2; ++ml)
#pragma unroll
        for (int ni = 0; ni < 4; ++ni)
#pragma unroll
            for (int r = 0; r < 4; ++r)
                P[swz((w << 5) + ml * 16 + q * 4 + r, ni * 16 + c)] =
                    (_Float16)fminf(fmaxf(acc[ml][ni][r], 0.0f), 1.0f);
    __syncthreads();                                  // B2: P complete

    // pass1 (x-blur): wave w computes output rows [32w, 32w+32)
    f32x4_t a2[2][4];
#pragma unroll
    for (int ml = 0; ml < 2; ++ml)
#pragma unroll
        for (int ni = 0; ni < 4; ++ni) a2[ml][ni] = (f32x4_t){0.f, 0.f, 0.f, 0.f};
#pragma unroll
    for (int hh = 0; hh < 2; ++hh) {
        half8_t af[2];
#pragma unroll
        for (int ml = 0; ml < 2; ++ml)
            af[ml] = *(const half8_t*)&P[swz(((w << 1) + ml) * 16 + c, hh * 32 + q * 8)];
#pragma unroll
        for (int ml = 0; ml < 2; ++ml)
#pragma unroll
            for (int ni = 0; ni < 4; ++ni)
                a2[ml][ni] = __builtin_amdgcn_mfma_f32_16x16x32_f16(
                    af[ml], gf[ni][hh], a2[ml][ni], 0, 0, 0);
    }
    // transpose into T (overlay B0); disjoint from P so no extra barrier needed
#pragma unroll
    for (int ml = 0; ml < 2; ++ml)
#pragma unroll
        for (int ni = 0; ni < 4; ++ni) {
            half4_t pkd;
#pragma unroll
            for (int r = 0; r < 4; ++r) pkd[r] = (_Float16)a2[ml][ni][r];
            *(half4_t*)&T[swz(ni * 16 + c, ((w << 1) + ml) * 16 + q * 4)] = pkd;
        }
    __syncthreads();                                  // B3: T complete

    // pass2 (y-blur): wave w computes output rows [32w, 32w+32)
    f32x4_t a3[2][4];
#pragma unroll
    for (int ml = 0; ml < 2; ++ml)
#pragma unroll
        for (int ni = 0; ni < 4; ++ni) a3[ml][ni] = (f32x4_t){0.f, 0.f, 0.f, 0.f};
#pragma unroll
    for (int hh = 0; hh < 2; ++hh) {
        half8_t bf[4];
#pragma unroll
        for (int ni = 0; ni < 4; ++ni)
            bf[ni] = *(const half8_t*)&T[swz(ni * 16 + c, hh * 32 + q * 8)];
#pragma unroll
        for (int ml = 0; ml < 2; ++ml)
#pragma unroll
            for (int ni = 0; ni < 4; ++ni)
                a3[ml][ni] = __builtin_amdgcn_mfma_f32_16x16x32_f16(
                    gf[(w << 1) + ml][hh], bf[ni], a3[ml][ni], 0, 0, 0);
    }

    // store f16 half-plane
    _Float16* dst = vox + ((size_t)b << 18) + ((size_t)z << 12);
#pragma unroll
    for (int ml = 0; ml < 2; ++ml)
#pragma unroll
        for (int ni = 0; ni < 4; ++ni)
#pragma unroll
            for (int r = 0; r < 4; ++r)
                dst[(((w << 5) + ml * 16 + q * 4 + r) << 6) + ni * 16 + c] =
                    (_Float16)a3[ml][ni][r];
}

// ---- 3. fused conv along z (f16 in) + scale/clip + segmented DRC + y-flip ----
__global__ void convz_drc_kernel(const _Float16* __restrict__ in,
                                 const float* __restrict__ scale,
                                 float* __restrict__ out) {
    __shared__ float sraw[640 + SZ * SZ + 640];  // 10-row zero guards each side
    __shared__ float c[SZ * SZ];
    __shared__ float segS[4][64], segT[4][64];
    float* s = sraw + 640;
    int b = blockIdx.x >> 6, y = blockIdx.x & 63;

    for (int i = threadIdx.x; i < 640; i += 256) {
        sraw[i] = 0.0f;
        sraw[640 + SZ * SZ + i] = 0.0f;
    }
    const _Float16* base = in + ((size_t)b << 18) + (y << 6);
#pragma unroll
    for (int g = 0; g < 4; ++g) {
        int cell = g * 256 + threadIdx.x;        // 1024 half4 cells
        int z = cell >> 4, xc = (cell & 15) << 2;
        half4_t v = *(const half4_t*)&base[((size_t)z << 12) + xc];
        float4 f = make_float4((float)v[0], (float)v[1], (float)v[2], (float)v[3]);
        *(float4*)&s[(z << 6) + xc] = f;
    }
    __syncthreads();

    float w[KS];
    weights_reg(w);

    {   // z-conv: one (z-group-of-4, x-chunk) per thread, 24 b128 reads
        int z0 = (threadIdx.x >> 4) << 2;
        int xc = (threadIdx.x & 15) << 2;
        float4 a0 = {0,0,0,0}, a1 = {0,0,0,0}, a2 = {0,0,0,0}, a3 = {0,0,0,0};
#pragma unroll
        for (int d = 0; d < 24; ++d) {
            int zz = z0 - HALF + d;              // guards cover [-10, 73]
            float4 v = *(const float4*)&s[(zz << 6) + xc];
            if (d <= 20)           fma4(a0, w[d],     v);
            if (d >= 1 && d <= 21) fma4(a1, w[d - 1], v);
            if (d >= 2 && d <= 22) fma4(a2, w[d - 2], v);
            if (d >= 3)            fma4(a3, w[d - 3], v);
        }
        *(float4*)&c[((z0 + 0) << 6) + xc] = a0;
        *(float4*)&c[((z0 + 1) << 6) + xc] = a1;
        *(float4*)&c[((z0 + 2) << 6) + xc] = a2;
        *(float4*)&c[((z0 + 3) << 6) + xc] = a3;
    }
    __syncthreads();

    {   // segmented DRC march: 4 z-segments x 64 columns
        int x = threadIdx.x & 63, seg = threadIdx.x >> 6;
        float sc = scale[b];
        float trans = 1.0f, sum = 0.0f;
#pragma unroll
        for (int zz = 0; zz < 16; ++zz) {
            int z = seg * 16 + zz;
            float v = fminf(fmaxf(c[(z << 6) + x] * sc, 0.0f), 1.0f);
            sum += v * trans;
            trans *= 1.0f - v;
        }
        segS[seg][x] = sum;
        segT[seg][x] = trans;
    }
    __syncthreads();
    if (threadIdx.x < 64) {
        int x = threadIdx.x;
        float t = 1.0f, S = 0.0f;
#pragma unroll
        for (int sgi = 0; sgi < 4; ++sgi) { S += segS[sgi][x] * t; t *= segT[sgi][x]; }
        out[(b << 12) + ((63 - y) << 6) + x] = S;
    }
}

extern "C" void kernel_launch(void* const* d_in, const int* in_sizes, int n_in,
                              void* d_out, int out_size, void* d_ws, size_t ws_size,
                              hipStream_t stream) {
    const float* pc    = (const float*)d_in[0];
    const float* rot   = (const float*)d_in[1];
    const float* scale = (const float*)d_in[2];
    float* out = (float*)d_out;

    // ws: vox f16 16.8 MB | binned sub-bins 42.6 MB | G 8 KB | cursors 16.6 KB
    _Float16* vox    = (_Float16*)d_ws;
    uint2*    binned = (uint2*)((char*)d_ws + (size_t)NB * SZ3 * sizeof(_Float16));
    _Float16* Gg     = (_Float16*)((char*)binned + (size_t)NB * NBIN2 * CAP2 * sizeof(uint2));
    int*      cur    = (int*)((char*)Gg + 64 * 64 * sizeof(_Float16));

    hipMemsetAsync(cur, 0, NB * NBIN2 * sizeof(int), stream);

    fill_kernel     <<<NB * NP / 1024, 256, 0, stream>>>(pc, rot, cur, binned, Gg);
    splat_blur      <<<NB * SZ, 128, 0, stream>>>(binned, cur, Gg, vox);
    convz_drc_kernel<<<NB * SZ, 256, 0, stream>>>(vox, scale, out);
}

// Round 6
// 121.010 us; speedup vs baseline: 1.6755x; 1.0726x over previous
//
#include <hip/hip_runtime.h>

#define NB    32
#define NP    65536
#define SZ    64
#define SZ3   (SZ * SZ * SZ)     // 262144
#define KS    21
#define HALF  10
#define NBIN2 130                // sub-bins: (i2+1)*2 + yhalf, i2 in [-1,63]
#define CAP2  1280               // fixed sub-bin capacity (max expected ~900)
#define FXS   960.0f             // fixed-point scale; (65+2)*960 = 64320 < 65535

typedef _Float16 half8_t __attribute__((ext_vector_type(8)));
typedef _Float16 half4_t __attribute__((ext_vector_type(4)));
typedef float    f32x4_t __attribute__((ext_vector_type(4)));

// XOR-swizzled tile address: rows x 64 cols of f16, 16B-chunk swizzle.
__device__ __forceinline__ int swz(int row, int col) {
    return (row << 6) + ((((col >> 3) ^ (row & 7))) << 3) + (col & 7);
}

// Normalized Gaussian taps (sigma=3) into registers
__device__ __forceinline__ void weights_reg(float* w) {
    float sum = 0.0f;
#pragma unroll
    for (int k = 0; k < KS; ++k) {
        float d = (float)k - (float)HALF;
        w[k] = expf(-d * d / 18.0f);
        sum += w[k];
    }
#pragma unroll
    for (int k = 0; k < KS; ++k) w[k] /= sum;
}

__device__ __forceinline__ unsigned pack_fx(float g) {
    float c = fminf(fmaxf(g, -2.0f), 65.0f);
    return (unsigned)__float2uint_rn((c + 2.0f) * FXS);
}

// ---- 1. fill (z, y-half) sub-bins (packed u16x4); straddlers duplicated ----
__global__ void fill_kernel(const float* __restrict__ pc,
                            const float* __restrict__ rot,
                            int* __restrict__ cur,
                            uint2* __restrict__ binned,
                            _Float16* __restrict__ Gg) {
    __shared__ int h[4][NBIN2];
    __shared__ int woff[4][NBIN2];
    __shared__ int lbase[NBIN2];
    int base = blockIdx.x * 1024;          // 4 points/thread, block within one batch
    int b = base >> 16;
    int wv = threadIdx.x >> 6;
    for (int i = threadIdx.x; i < 4 * NBIN2; i += 256) h[i / NBIN2][i % NBIN2] = 0;
    __syncthreads();
    const float* R = rot + b * 9;
    const float4* p4 = (const float4*)(pc + (size_t)base * 3);
    float4 f0 = p4[threadIdx.x * 3 + 0];
    float4 f1 = p4[threadIdx.x * 3 + 1];
    float4 f2 = p4[threadIdx.x * 3 + 2];
    float px[4] = {f0.x, f0.w, f1.z, f2.y};
    float py[4] = {f0.y, f1.x, f1.w, f2.z};
    float pz[4] = {f0.z, f1.y, f2.x, f2.w};
    uint2 pk[4];
    int bin0[4], bin1[4], lp0[4], lp1[4];
#pragma unroll
    for (int j = 0; j < 4; ++j) {
        float g0 = (R[0] * px[j] + R[1] * py[j] + R[2] * pz[j] + 0.5f) * 63.0f;
        float g1 = (R[3] * px[j] + R[4] * py[j] + R[5] * pz[j] + 0.5f) * 63.0f;
        float g2 = (R[6] * px[j] + R[7] * py[j] + R[8] * pz[j] + 0.5f) * 63.0f;
        int i2 = (int)floorf(g2);
        int i1 = (int)floorf(g1);
        bool zv = (i2 >= -1 && i2 <= 63);
        int h0 = ((unsigned)i1       < 64u) ? (i1 >> 5)       : -1;
        int h1 = ((unsigned)(i1 + 1) < 64u) ? ((i1 + 1) >> 5) : -1;
        if (h1 == h0) h1 = -1;
        bin0[j] = (zv && h0 >= 0) ? ((i2 + 1) * 2 + h0) : -1;
        bin1[j] = (zv && h1 >= 0) ? ((i2 + 1) * 2 + h1) : -1;
        pk[j] = make_uint2(pack_fx(g0) | (pack_fx(g1) << 16), pack_fx(g2));
        if (bin0[j] >= 0) lp0[j] = atomicAdd(&h[wv][bin0[j]], 1);
        if (bin1[j] >= 0) lp1[j] = atomicAdd(&h[wv][bin1[j]], 1);
    }
    __syncthreads();
    if (threadIdx.x < NBIN2) {
        int t = threadIdx.x;
        int s0 = h[0][t], s1 = h[1][t], s2 = h[2][t], s3 = h[3][t];
        int tot = s0 + s1 + s2 + s3;
        lbase[t] = tot ? atomicAdd(&cur[b * NBIN2 + t], tot) : 0;
        woff[0][t] = 0; woff[1][t] = s0; woff[2][t] = s0 + s1; woff[3][t] = s0 + s1 + s2;
    }
    __syncthreads();
#pragma unroll
    for (int j = 0; j < 4; ++j) {
        if (bin0[j] >= 0) {
            int pos = lbase[bin0[j]] + woff[wv][bin0[j]] + lp0[j];
            if (pos < CAP2)
                binned[(size_t)(b * NBIN2 + bin0[j]) * CAP2 + pos] = pk[j];
        }
        if (bin1[j] >= 0) {
            int pos = lbase[bin1[j]] + woff[wv][bin1[j]] + lp1[j];
            if (pos < CAP2)
                binned[(size_t)(b * NBIN2 + bin1[j]) * CAP2 + pos] = pk[j];
        }
    }
    // G[o][k] = g[o-k+10] (zero outside band), row-major stride 64
    if (blockIdx.x == 0) {
        float w[KS];
        weights_reg(w);
        for (int i = threadIdx.x; i < 4096; i += 256) {
            int d = (i >> 6) - (i & 63) + HALF;
            Gg[i] = ((unsigned)d < (unsigned)KS) ? (_Float16)w[d] : (_Float16)0.0f;
        }
    }
}

// ---- 2. MFMA splat + blur. TWO WAVES per (b,z): each owns one y-half. ----
// (byte-identical to the 121.7us champion)
__global__ void __launch_bounds__(128) splat_blur(const uint2* __restrict__ binned,
                                                  const int* __restrict__ cur,
                                                  const _Float16* __restrict__ Gg,
                                                  _Float16* __restrict__ vox) {
    // layout: A0[0,4224) A1[4224,8448) B0[8448,16768) B1[16768,25088)
    // overlays (dead after scatter): P=[0,8192)  T=[8448,16640)
    __shared__ __align__(16) char smem[25088];
    int tid = threadIdx.x;
    int w = tid >> 6, lane = tid & 63;
    int idx = blockIdx.x;
    int b = idx >> 6;
    int k = (idx + (b << 3)) & 63;                    // shear for per-CU mix
    int z = (k & 1) ? (31 - (k >> 1)) : (32 + (k >> 1));  // center-out (LPT)
    int q = lane >> 4, c = lane & 15;

    _Float16* Ay = (_Float16*)(smem + w * 4224);      // 33 rows (32 real + dummy 32)
    _Float16* Bx = (_Float16*)(smem + 8448 + w * 8320); // 65 rows (dummy 64)
    _Float16* P  = (_Float16*)smem;
    _Float16* T  = (_Float16*)(smem + 8448);

    {   // zero own tiles (wave-local, wave-ordered)
        int4 z4 = {0, 0, 0, 0};
        int4* a4 = (int4*)Ay;
        for (int i = lane; i < 4224 / 16; i += 64) a4[i] = z4;
        int4* b4 = (int4*)Bx;
        for (int i = lane; i < 8320 / 16; i += 64) b4[i] = z4;
    }

    // G fragments (both waves load all 4; one pattern serves both passes)
    half8_t gf[4][2];
#pragma unroll
    for (int ni = 0; ni < 4; ++ni)
#pragma unroll
        for (int hh = 0; hh < 2; ++hh)
            gf[ni][hh] = *(const half8_t*)&Gg[(ni * 16 + c) * 64 + hh * 32 + q * 8];

    // this wave's sub-bins: (i2=z-1, w) and (i2=z, w)
    int c0 = min(cur[b * NBIN2 + 2 * z + w],       CAP2);
    int c1 = min(cur[b * NBIN2 + 2 * (z + 1) + w], CAP2);
    const uint2* s0 = binned + (size_t)(b * NBIN2 + 2 * z + w) * CAP2;
    const uint2* s1 = binned + (size_t)(b * NBIN2 + 2 * (z + 1) + w) * CAP2;
    int n = c0 + c1;

    f32x4_t acc[2][4];
#pragma unroll
    for (int ml = 0; ml < 2; ++ml)
#pragma unroll
        for (int ni = 0; ni < 4; ++ni) acc[ml][ni] = (f32x4_t){0.f, 0.f, 0.f, 0.f};

    int iters = (n + 63) >> 6;
    uint2 nxtA = make_uint2(0u, 0u), nxtB = make_uint2(0u, 0u);  // gz=-2 -> az=0
    {
        int i0g = lane;
        if (i0g < n) nxtA = (i0g < c0) ? s0[i0g] : s1[i0g - c0];
        int i1g = 64 + lane;
        if (i1g < n) nxtB = (i1g < c0) ? s0[i1g] : s1[i1g - c0];
    }
    for (int it = 0; it < iters; ++it) {
        uint2 pk = nxtA;
        nxtA = nxtB;
        nxtB = make_uint2(0u, 0u);
        int ni2 = (it + 2) * 64 + lane;               // prefetch depth 2
        if (ni2 < n) nxtB = (ni2 < c0) ? s0[ni2] : s1[ni2 - c0];

        float gx = (float)(pk.x & 0xffffu) * (1.0f / FXS) - 2.0f;
        float gy = (float)(pk.x >> 16)     * (1.0f / FXS) - 2.0f;
        float gz = (float)(pk.y & 0xffffu) * (1.0f / FXS) - 2.0f;
        float f0 = floorf(gx), f1 = floorf(gy);
        int   i0 = (int)f0,    i1 = (int)f1;
        float r0 = gx - f0,    r1f = gy - f1;
        float az = fmaxf(0.0f, 1.0f - fabsf(gz - (float)z));
        int rlo = i1 - (w << 5), rhi = i1 + 1 - (w << 5);
        int alo = ((unsigned)rlo < 32u) ? rlo : 32;   // dummy row 32
        int ahi = ((unsigned)rhi < 32u) ? rhi : 32;
        int xlo = ((unsigned)i0       < 64u) ? i0       : 64;
        int xhi = ((unsigned)(i0 + 1) < 64u) ? (i0 + 1) : 64;
        Ay[swz(alo, lane)] = (_Float16)(az * (1.0f - r1f));
        Ay[swz(ahi, lane)] = (_Float16)(az * r1f);
        Bx[swz(xlo, lane)] = (_Float16)(1.0f - r0);
        Bx[swz(xhi, lane)] = (_Float16)r0;
#pragma unroll
        for (int hh = 0; hh < 2; ++hh) {
            half8_t af[2], bf[4];
#pragma unroll
            for (int ml = 0; ml < 2; ++ml)
                af[ml] = *(const half8_t*)&Ay[swz(ml * 16 + c, hh * 32 + q * 8)];
#pragma unroll
            for (int ni = 0; ni < 4; ++ni)
                bf[ni] = *(const half8_t*)&Bx[swz(ni * 16 + c, hh * 32 + q * 8)];
#pragma unroll
            for (int ml = 0; ml < 2; ++ml)
#pragma unroll
                for (int ni = 0; ni < 4; ++ni)
                    acc[ml][ni] = __builtin_amdgcn_mfma_f32_16x16x32_f16(
                        af[ml], bf[ni], acc[ml][ni], 0, 0, 0);
        }
        // re-zero exactly what we wrote (after the frag reads; wave-ordered)
        Ay[swz(alo, lane)] = (_Float16)0.0f;
        Ay[swz(ahi, lane)] = (_Float16)0.0f;
        Bx[swz(xlo, lane)] = (_Float16)0.0f;
        Bx[swz(xhi, lane)] = (_Float16)0.0f;
    }

    __syncthreads();                                  // B1: all scatter done

    // each wave writes its clipped half-plane into shared P (overlay A0/A1)
#pragma unroll
    for (int ml = 0; ml < 2; ++ml)
#pragma unroll
        for (int ni = 0; ni < 4; ++ni)
#pragma unroll
            for (int r = 0; r < 4; ++r)
                P[swz((w << 5) + ml * 16 + q * 4 + r, ni * 16 + c)] =
                    (_Float16)fminf(fmaxf(acc[ml][ni][r], 0.0f), 1.0f);
    __syncthreads();                                  // B2: P complete

    // pass1 (x-blur): wave w computes output rows [32w, 32w+32)
    f32x4_t a2[2][4];
#pragma unroll
    for (int ml = 0; ml < 2; ++ml)
#pragma unroll
        for (int ni = 0; ni < 4; ++ni) a2[ml][ni] = (f32x4_t){0.f, 0.f, 0.f, 0.f};
#pragma unroll
    for (int hh = 0; hh < 2; ++hh) {
        half8_t af[2];
#pragma unroll
        for (int ml = 0; ml < 2; ++ml)
            af[ml] = *(const half8_t*)&P[swz(((w << 1) + ml) * 16 + c, hh * 32 + q * 8)];
#pragma unroll
        for (int ml = 0; ml < 2; ++ml)
#pragma unroll
            for (int ni = 0; ni < 4; ++ni)
                a2[ml][ni] = __builtin_amdgcn_mfma_f32_16x16x32_f16(
                    af[ml], gf[ni][hh], a2[ml][ni], 0, 0, 0);
    }
    // transpose into T (overlay B0); disjoint from P so no extra barrier needed
#pragma unroll
    for (int ml = 0; ml < 2; ++ml)
#pragma unroll
        for (int ni = 0; ni < 4; ++ni) {
            half4_t pkd;
#pragma unroll
            for (int r = 0; r < 4; ++r) pkd[r] = (_Float16)a2[ml][ni][r];
            *(half4_t*)&T[swz(ni * 16 + c, ((w << 1) + ml) * 16 + q * 4)] = pkd;
        }
    __syncthreads();                                  // B3: T complete

    // pass2 (y-blur): wave w computes output rows [32w, 32w+32)
    f32x4_t a3[2][4];
#pragma unroll
    for (int ml = 0; ml < 2; ++ml)
#pragma unroll
        for (int ni = 0; ni < 4; ++ni) a3[ml][ni] = (f32x4_t){0.f, 0.f, 0.f, 0.f};
#pragma unroll
    for (int hh = 0; hh < 2; ++hh) {
        half8_t bf[4];
#pragma unroll
        for (int ni = 0; ni < 4; ++ni)
            bf[ni] = *(const half8_t*)&T[swz(ni * 16 + c, hh * 32 + q * 8)];
#pragma unroll
        for (int ml = 0; ml < 2; ++ml)
#pragma unroll
            for (int ni = 0; ni < 4; ++ni)
                a3[ml][ni] = __builtin_amdgcn_mfma_f32_16x16x32_f16(
                    gf[(w << 1) + ml][hh], bf[ni], a3[ml][ni], 0, 0, 0);
    }

    // store f16 half-plane
    _Float16* dst = vox + ((size_t)b << 18) + ((size_t)z << 12);
#pragma unroll
    for (int ml = 0; ml < 2; ++ml)
#pragma unroll
        for (int ni = 0; ni < 4; ++ni)
#pragma unroll
            for (int r = 0; r < 4; ++r)
                dst[(((w << 5) + ml * 16 + q * 4 + r) << 6) + ni * 16 + c] =
                    (_Float16)a3[ml][ni][r];
}

// ---- 3. MFMA conv along z + scale/clip + segmented DRC + y-flip ----
// z-'SAME' Gaussian conv == banded-G matmul: out[zo][x] = sum_zz G[zo][zz]V[zz][x]
// (boundary zero-padding is exactly the zero band of G). Stage V z-contiguous
// via register 4x4 transpose; 4 waves x 16 output z-rows each.
__global__ void convz_drc_kernel(const _Float16* __restrict__ in,
                                 const _Float16* __restrict__ Gg,
                                 const float* __restrict__ scale,
                                 float* __restrict__ out) {
#define CW 68                                  // c row stride (bank-clean)
    __shared__ __align__(16) _Float16 Vt[4096];  // swizzled, rows=x, cols=z
    __shared__ float c[SZ * CW];
    __shared__ float segS[4][64], segT[4][64];
    int tid = threadIdx.x;
    int w = tid >> 6, lane = tid & 63;
    int q = lane >> 4, cc = lane & 15;
    int b = blockIdx.x >> 6, y = blockIdx.x & 63;

    {   // stage: thread (xq,zq) loads 4x4 block of V[z][x], transposes in regs
        const _Float16* base = in + ((size_t)b << 18) + (y << 6);
        int xq = (tid & 15) << 2, zq = (tid >> 4) << 2;
        half4_t r0 = *(const half4_t*)&base[((size_t)(zq + 0) << 12) + xq];
        half4_t r1 = *(const half4_t*)&base[((size_t)(zq + 1) << 12) + xq];
        half4_t r2 = *(const half4_t*)&base[((size_t)(zq + 2) << 12) + xq];
        half4_t r3 = *(const half4_t*)&base[((size_t)(zq + 3) << 12) + xq];
#pragma unroll
        for (int i = 0; i < 4; ++i) {
            half4_t tc = {r0[i], r1[i], r2[i], r3[i]};
            *(half4_t*)&Vt[swz(xq + i, zq)] = tc;    // zq%8 in {0,4}: aligned
        }
    }
    __syncthreads();

    // G A-fragments for this wave's output z-rows [16w, 16w+16)  (L2-hot)
    half8_t af[2];
    af[0] = *(const half8_t*)&Gg[(w * 16 + cc) * 64 + q * 8];
    af[1] = *(const half8_t*)&Gg[(w * 16 + cc) * 64 + 32 + q * 8];

    f32x4_t a3[4];
#pragma unroll
    for (int ni = 0; ni < 4; ++ni) a3[ni] = (f32x4_t){0.f, 0.f, 0.f, 0.f};
#pragma unroll
    for (int hh = 0; hh < 2; ++hh) {
        half8_t bf[4];
#pragma unroll
        for (int ni = 0; ni < 4; ++ni)
            bf[ni] = *(const half8_t*)&Vt[swz(ni * 16 + cc, hh * 32 + q * 8)];
#pragma unroll
        for (int ni = 0; ni < 4; ++ni)
            a3[ni] = __builtin_amdgcn_mfma_f32_16x16x32_f16(
                af[hh], bf[ni], a3[ni], 0, 0, 0);
    }
    // write conv result (f32) to c
#pragma unroll
    for (int ni = 0; ni < 4; ++ni)
#pragma unroll
        for (int r = 0; r < 4; ++r)
            c[(w * 16 + q * 4 + r) * CW + ni * 16 + cc] = a3[ni][r];
    __syncthreads();

    {   // segmented DRC march: 4 z-segments x 64 columns
        int x = lane, seg = w;
        float sc = scale[b];
        float trans = 1.0f, sum = 0.0f;
#pragma unroll
        for (int zz = 0; zz < 16; ++zz) {
            int z = seg * 16 + zz;
            float v = fminf(fmaxf(c[z * CW + x] * sc, 0.0f), 1.0f);
            sum += v * trans;
            trans *= 1.0f - v;
        }
        segS[seg][x] = sum;
        segT[seg][x] = trans;
    }
    __syncthreads();
    if (threadIdx.x < 64) {
        int x = threadIdx.x;
        float t = 1.0f, S = 0.0f;
#pragma unroll
        for (int sgi = 0; sgi < 4; ++sgi) { S += segS[sgi][x] * t; t *= segT[sgi][x]; }
        out[(b << 12) + ((63 - y) << 6) + x] = S;
    }
#undef CW
}

extern "C" void kernel_launch(void* const* d_in, const int* in_sizes, int n_in,
                              void* d_out, int out_size, void* d_ws, size_t ws_size,
                              hipStream_t stream) {
    const float* pc    = (const float*)d_in[0];
    const float* rot   = (const float*)d_in[1];
    const float* scale = (const float*)d_in[2];
    float* out = (float*)d_out;

    // ws: vox f16 16.8 MB | binned sub-bins 42.6 MB | G 8 KB | cursors 16.6 KB
    _Float16* vox    = (_Float16*)d_ws;
    uint2*    binned = (uint2*)((char*)d_ws + (size_t)NB * SZ3 * sizeof(_Float16));
    _Float16* Gg     = (_Float16*)((char*)binned + (size_t)NB * NBIN2 * CAP2 * sizeof(uint2));
    int*      cur    = (int*)((char*)Gg + 64 * 64 * sizeof(_Float16));

    hipMemsetAsync(cur, 0, NB * NBIN2 * sizeof(int), stream);

    fill_kernel     <<<NB * NP / 1024, 256, 0, stream>>>(pc, rot, cur, binned, Gg);
    splat_blur      <<<NB * SZ, 128, 0, stream>>>(binned, cur, Gg, vox);
    convz_drc_kernel<<<NB * SZ, 256, 0, stream>>>(vox, Gg, scale, out);
}